// Round 15
// baseline (2401.232 us; speedup 1.0000x reference)
//
#include <hip/hip_runtime.h>
#include <cstdint>
#include <cstddef>

#define F_CH 76
#define T_LEN 4096
#define B_TOT 64
#define C_CLS 15
#define NSTEP 8

// ---- dual-slab fused-2-step kernel geometry ----
#define SLABW  112           // output t per slab (halo 8 each side, 2 RK4 steps)
#define BLKW   224           // output t per block (2 slabs)
#define HALO2  8
#define NBT    19            // ceil(4096/224)
#define NKB    5             // k-blocks of 16 (ci padded to 80)
#define WSTR   88            // weight row stride in bf16 (global wpb)
#define SST    128           // s_lds row stride in bf16 (16 slots of 8; XOR-bijective)
#define SROWS  130           // 128 compute rows + 2 halo
#define TPB    768           // 12 waves: (ct 0..2) x (tq 0..3)
#define HP     80            // h global row pitch (bf16 elems)

#define C2LOG2E 2.8853900817779268f   // 2*log2(e)

typedef __attribute__((ext_vector_type(8)))  __bf16 bf16x8;
typedef __attribute__((ext_vector_type(4)))  __bf16 bf16x4;
typedef __attribute__((ext_vector_type(16))) float  f32x16;
typedef __attribute__((ext_vector_type(4)))  float  f32x4;

// swizzled element offset of 8-elem slot `v` (0..15) in LDS row `r`; bijective
__device__ __forceinline__ int sw_off(int r, int v) {
    return r * SST + (((v) ^ (r & 15)) << 3);
}

// ---------------- pad-copy: x [B,T,76] f32 -> h [Bc,T,80] bf16 ----------------
__global__ __launch_bounds__(256) void pad_copy_kernel(
    const float* __restrict__ x, __bf16* __restrict__ h, int b0)
{
    int bl = blockIdx.y;
    int q  = blockIdx.x * 256 + threadIdx.x;
    int t  = q / 20, c4 = (q - t * 20) * 4;
    float4 v = {0.f, 0.f, 0.f, 0.f};
    if (c4 < F_CH)
        v = *(const float4*)(x + ((size_t)(b0 + bl) * T_LEN + t) * F_CH + c4);
    bf16x4 p;
    p[0] = (__bf16)v.x; p[1] = (__bf16)v.y; p[2] = (__bf16)v.z; p[3] = (__bf16)v.w;
    *(bf16x4*)(h + ((size_t)bl * T_LEN + t) * HP + c4) = p;
}

// ---- weight prep: cw [76][76][3] f32 -> wpb [3][96][WSTR] bf16 (zero-padded) ----
__global__ __launch_bounds__(256) void wprep_kernel(
    const float* __restrict__ cw, __bf16* __restrict__ wpb)
{
    int idx = blockIdx.x * 256 + threadIdx.x;
    if (idx >= 3 * 96 * WSTR) return;
    int tap = idx / (96 * WSTR);
    int rem = idx - tap * 96 * WSTR;
    int c = rem / WSTR, ci = rem - c * WSTR;
    float v = 0.0f;
    if (c < F_CH && ci < F_CH) v = cw[((size_t)c * F_CH + ci) * 3 + tap];
    wpb[idx] = (__bf16)v;
}

// one conv eval: taps 0,1 from registers; tap 2 A-frags streamed from L2
__device__ __forceinline__ f32x16 conv_eval(
    const __bf16* __restrict__ sb, const __bf16* __restrict__ w2base,
    int rb, int l5, const bf16x8 afr[2][NKB])
{
    bf16x8 a2[NKB];
    #pragma unroll
    for (int kb = 0; kb < NKB; ++kb)
        a2[kb] = *(const bf16x8*)(w2base + kb * 16);

    f32x16 a = {};
    #pragma unroll
    for (int tap = 0; tap < 2; ++tap) {
        #pragma unroll
        for (int kb = 0; kb < NKB; ++kb) {
            bf16x8 bf = *(const bf16x8*)&sb[sw_off(rb + tap, kb * 2 + l5)];
            a = __builtin_amdgcn_mfma_f32_32x32x16_bf16(afr[tap][kb], bf, a, 0, 0, 0);
        }
    }
    #pragma unroll
    for (int kb = 0; kb < NKB; ++kb) {
        bf16x8 bf = *(const bf16x8*)&sb[sw_off(rb + 2, kb * 2 + l5)];
        a = __builtin_amdgcn_mfma_f32_32x32x16_bf16(a2[kb], bf, a, 0, 0, 0);
    }
    return a;
}

// ---------- dual-slab fused 2x RK4 steps ----------
__global__ __launch_bounds__(TPB, 3) void rk4_step2_kernel(
    const __bf16* __restrict__ hin, __bf16* __restrict__ hout,
    const __bf16* __restrict__ wpb, const float* __restrict__ cb)
{
    __shared__ __bf16 s_lds[3][SROWS * SST];
    __shared__ float  cb_lds[96];

    const int b    = blockIdx.y;
    const int T0A  = blockIdx.x * BLKW;
    const int T0B  = T0A + SLABW;
    const int tid  = threadIdx.x;
    const int lane = tid & 63;
    const int l31  = lane & 31;
    const int l5   = lane >> 5;          // 0..1
    const int wv   = tid >> 6;           // 0..11
    const int ct   = wv >> 2;            // c-tile 0..2
    const int tq   = wv & 3;             // t-tile 0..3

    const int  rb   = tq * 32 + l31;     // row base 0..127
    const int  tgA  = T0A - HALO2 + rb;
    const int  tgB  = T0B - HALO2 + rb;
    const bool tokA = (tgA >= 0 && tgA < T_LEN);
    const bool tokB = (tgB >= 0 && tgB < T_LEN);

    // zero the 6 halo rows (3 buffers x rows {0, SROWS-1} x 64 dwords)
    if (tid < 384) {
        int buf = tid / 128, rr = (tid % 128) / 64, c = tid % 64;
        ((uint32_t*)&s_lds[buf][(rr ? (SROWS - 1) : 0) * SST])[c] = 0u;
    }
    if (tid < 96) cb_lds[tid] = (tid < F_CH) ? cb[tid] * C2LOG2E : 0.0f;

    // ---- load h (bf16) for both slabs ----
    float  hnA[16], hnB[16];
    bf16x4 hpkA[4], hpkB[4];
    const __bf16* hb = hin + (size_t)b * T_LEN * HP;
    #pragma unroll
    for (int q = 0; q < 4; ++q) {
        int c0 = ct * 32 + l5 * 4 + q * 8;
        bf16x4 vA = {}, vB = {};
        if (c0 < HP) {
            if (tokA) vA = *(const bf16x4*)(hb + (size_t)tgA * HP + c0);
            if (tokB) vB = *(const bf16x4*)(hb + (size_t)tgB * HP + c0);
        }
        hpkA[q] = vA; hpkB[q] = vB;
        hnA[q*4+0] = (float)vA[0]; hnA[q*4+1] = (float)vA[1];
        hnA[q*4+2] = (float)vA[2]; hnA[q*4+3] = (float)vA[3];
        hnB[q*4+0] = (float)vB[0]; hnB[q*4+1] = (float)vB[1];
        hnB[q*4+2] = (float)vB[2]; hnB[q*4+3] = (float)vB[3];
    }

    // ---- A fragments: taps 0,1 in registers; tap-2 base pointer for streaming ----
    bf16x8 afr[2][NKB];
    #pragma unroll
    for (int tap = 0; tap < 2; ++tap)
        #pragma unroll
        for (int kb = 0; kb < NKB; ++kb)
            afr[tap][kb] = *(const bf16x8*)&wpb[((size_t)tap * 96 + ct * 32 + l31) * WSTR
                                                + kb * 16 + l5 * 8];
    const __bf16* w2base = wpb + ((size_t)2 * 96 + ct * 32 + l31) * WSTR + l5 * 8;

    __bf16* p0 = s_lds[0];
    __bf16* p1 = s_lds[1];
    __bf16* p2 = s_lds[2];

    // ---- prologue: stage A -> p0 ; barrier ; MFMA_A(0) + stage B -> p2 ----
    #pragma unroll
    for (int q = 0; q < 4; ++q) {
        int c0 = ct * 32 + l5 * 4 + q * 8;
        if (c0 < HP) *(bf16x4*)&p0[sw_off(rb + 1, ct * 4 + q) + l5 * 4] = hpkA[q];
    }
    __syncthreads();

    f32x16 accA = conv_eval(p0, w2base, rb, l5, afr);
    #pragma unroll
    for (int q = 0; q < 4; ++q) {
        int c0 = ct * 32 + l5 * 4 + q * 8;
        if (c0 < HP) *(bf16x4*)&p2[sw_off(rb + 1, ct * 4 + q) + l5 * 4] = hpkB[q];
    }
    __syncthreads();

    const float dt = 0.125f;
    f32x16 accB;

#define EPI(acc, hn, hpk, tokX, swp)                                          \
    {                                                                         \
        const float al_t = (tokX) ? al : 0.0f;                                \
        _Pragma("unroll")                                                     \
        for (int q = 0; q < 4; ++q) {                                         \
            int c0 = ct * 32 + l5 * 4 + q * 8;                                \
            if (c0 >= HP) continue;                                           \
            f32x4 bias = *(const f32x4*)&cb_lds[c0];                          \
            bf16x4 p;                                                         \
            _Pragma("unroll")                                                 \
            for (int j = 0; j < 4; ++j) {                                     \
                float y  = fmaf((acc)[q*4+j], C2LOG2E, bias[j]);              \
                float ex = __builtin_amdgcn_exp2f(y);                         \
                float kv = fmaf(-2.0f, __builtin_amdgcn_rcpf(ex + 1.0f), 1.0f); \
                (hn)[q*4+j] = fmaf(we, kv, (hn)[q*4+j]);                      \
                p[j] = (__bf16)fmaf(al_t, kv, (float)(hpk)[q][j]);            \
            }                                                                 \
            if (!laststage)                                                   \
                *(bf16x4*)&(swp)[sw_off(rb + 1, ct * 4 + q) + l5 * 4] = p;    \
        }                                                                     \
        if (restage) {                                                        \
            _Pragma("unroll")                                                 \
            for (int i = 0; i < 16; ++i) (hn)[i] = (tokX) ? (hn)[i] : 0.0f;   \
            _Pragma("unroll")                                                 \
            for (int q = 0; q < 4; ++q) {                                     \
                int c0 = ct * 32 + l5 * 4 + q * 8;                            \
                _Pragma("unroll")                                             \
                for (int j = 0; j < 4; ++j) (hpk)[q][j] = (__bf16)(hn)[q*4+j];\
                if (c0 < HP)                                                  \
                    *(bf16x4*)&(swp)[sw_off(rb + 1, ct * 4 + q) + l5 * 4] = (hpk)[q]; \
            }                                                                 \
        }                                                                     \
    }

    #pragma unroll 1
    for (int ge = 0; ge < 8; ++ge) {
        const float we = (((ge & 3) == 0) || ((ge & 3) == 3)) ? dt / 6.0f : dt / 3.0f;
        const float al = ((ge & 3) == 2) ? dt : 0.5f * dt;
        const bool laststage = ((ge & 3) == 3);   // evals 3,7: no normal stage write
        const bool restage   = (ge == 3);         // end of step 1: restage h1

        // HPa: MFMA_B(ge) reads p2 || EPI_A(ge) writes p1
        accB = conv_eval(p2, w2base, rb, l5, afr);
        EPI(accA, hnA, hpkA, tokA, p1);
        __syncthreads();

        // HPb: MFMA_A(ge+1) reads p1 || EPI_B(ge) writes p0
        if (ge < 7) accA = conv_eval(p1, w2base, rb, l5, afr);
        EPI(accB, hnB, hpkB, tokB, p0);
        if (ge < 7) __syncthreads();

        // rotate buffers
        __bf16* t = p0; p0 = p1; p1 = p2; p2 = t;
    }
#undef EPI

    // ---- store both slabs (valid rows [HALO2, HALO2+SLABW)) ----
    __bf16* ho = hout + (size_t)b * T_LEN * HP;
    if (rb >= HALO2 && rb < HALO2 + SLABW && tgA < T_LEN) {
        #pragma unroll
        for (int q = 0; q < 4; ++q) {
            int c0 = ct * 32 + l5 * 4 + q * 8;
            if (c0 < HP) {
                bf16x4 p;
                p[0] = (__bf16)hnA[q*4+0]; p[1] = (__bf16)hnA[q*4+1];
                p[2] = (__bf16)hnA[q*4+2]; p[3] = (__bf16)hnA[q*4+3];
                *(bf16x4*)(ho + (size_t)tgA * HP + c0) = p;
            }
        }
    }
    if (rb >= HALO2 && rb < HALO2 + SLABW && tgB < T_LEN) {
        #pragma unroll
        for (int q = 0; q < 4; ++q) {
            int c0 = ct * 32 + l5 * 4 + q * 8;
            if (c0 < HP) {
                bf16x4 p;
                p[0] = (__bf16)hnB[q*4+0]; p[1] = (__bf16)hnB[q*4+1];
                p[2] = (__bf16)hnB[q*4+2]; p[3] = (__bf16)hnB[q*4+3];
                *(bf16x4*)(ho + (size_t)tgB * HP + c0) = p;
            }
        }
    }
}

// ------------- final linear: out[b,t,c] = sum_f h[t][f]*fw[c,f] + fb[c] -------------
__global__ __launch_bounds__(256) void final_kernel(
    const __bf16* __restrict__ h, const float* __restrict__ fw,
    const float* __restrict__ fb, float* __restrict__ out, int b0)
{
    int bl = blockIdx.y;
    int t  = blockIdx.x * 256 + threadIdx.x;
    const __bf16* hr = h + ((size_t)bl * T_LEN + t) * HP;
    float acc[C_CLS];
#pragma unroll
    for (int c = 0; c < C_CLS; ++c) acc[c] = fb[c];
#pragma unroll
    for (int qf = 0; qf < 19; ++qf) {
        bf16x4 v4 = *(const bf16x4*)(hr + qf * 4);
        float v0 = (float)v4[0], v1 = (float)v4[1], v2 = (float)v4[2], v3 = (float)v4[3];
#pragma unroll
        for (int c = 0; c < C_CLS; ++c) {
            const float* w = fw + c * F_CH + qf * 4;
            acc[c] = fmaf(w[0], v0, acc[c]);
            acc[c] = fmaf(w[1], v1, acc[c]);
            acc[c] = fmaf(w[2], v2, acc[c]);
            acc[c] = fmaf(w[3], v3, acc[c]);
        }
    }
    float* ob = out + ((size_t)(b0 + bl) * T_LEN + t) * C_CLS;
#pragma unroll
    for (int c = 0; c < C_CLS; ++c) ob[c] = acc[c];
}

extern "C" void kernel_launch(void* const* d_in, const int* in_sizes, int n_in,
                              void* d_out, int out_size, void* d_ws, size_t ws_size,
                              hipStream_t stream)
{
    const float* x  = (const float*)d_in[0];
    const float* cw = (const float*)d_in[1];
    const float* cb = (const float*)d_in[2];
    const float* fw = (const float*)d_in[3];
    const float* fb = (const float*)d_in[4];
    float* out = (float*)d_out;

    const size_t FT = (size_t)T_LEN * HP;            // bf16 elems per batch plane

    __bf16* WPB = (__bf16*)d_ws;
    const size_t wpbBytes = 51200;                   // 3*96*88 bf16, padded/aligned
    __bf16* planes = (__bf16*)((char*)d_ws + wpbBytes);

    size_t planeBytes = 2 * FT * sizeof(__bf16);
    size_t avail = ws_size - wpbBytes;
    int Bc = (int)(avail / planeBytes);
    if (Bc > B_TOT) Bc = B_TOT;
    if (Bc < 1) Bc = 1;

    __bf16* H0 = planes;
    __bf16* H1 = H0 + (size_t)Bc * FT;

    wprep_kernel<<<(3 * 96 * WSTR + 255) / 256, 256, 0, stream>>>(cw, WPB);

    for (int b0 = 0; b0 < B_TOT; b0 += Bc) {
        int bc = (B_TOT - b0 < Bc) ? (B_TOT - b0) : Bc;

        dim3 gP(T_LEN * 20 / 256, bc);
        pad_copy_kernel<<<gP, 256, 0, stream>>>(x, H0, b0);

        __bf16* hcur = H0;
        __bf16* hnxt = H1;
        dim3 gR(NBT, bc);
        for (int st2 = 0; st2 < NSTEP / 2; ++st2) {
            rk4_step2_kernel<<<gR, TPB, 0, stream>>>(hcur, hnxt, WPB, cb);
            __bf16* tmp = hcur; hcur = hnxt; hnxt = tmp;
        }

        dim3 gF(T_LEN / 256, bc);
        final_kernel<<<gF, 256, 0, stream>>>(hcur, fw, fb, out, b0);
    }
}

// Round 16
// 938.681 us; speedup vs baseline: 2.5581x; 2.5581x over previous
//
#include <hip/hip_runtime.h>
#include <cstdint>
#include <cstddef>

#define F_CH 76
#define T_LEN 4096
#define B_TOT 64
#define C_CLS 15
#define NSTEP 8

// ---- dual-slab 1-step RK4 kernel geometry ----
#define SLABW  56            // output t per slab (halo 4 each side, 1 RK4 step)
#define BLKW   112           // output t per block (2 slabs)
#define HALO   4
#define NBT    37            // ceil(4096/112)
#define NKB    5             // k-blocks of 16 (ci padded to 80)
#define WSTR   88            // weight row stride in bf16 (global wpb)
#define SST    128           // s_lds row stride in bf16 (16 slots of 8; XOR-bijective)
#define SROWS  66            // 64 compute rows + 2 halo
#define TPB    384           // 6 waves: (ct 0..2) x (tq 0..1)
#define HP     80            // h global row pitch (bf16 elems)

#define C2LOG2E 2.8853900817779268f   // 2*log2(e)

typedef __attribute__((ext_vector_type(8)))  __bf16 bf16x8;
typedef __attribute__((ext_vector_type(4)))  __bf16 bf16x4;
typedef __attribute__((ext_vector_type(16))) float  f32x16;
typedef __attribute__((ext_vector_type(4)))  float  f32x4;

// swizzled element offset of 8-elem slot `v` (0..15) in LDS row `r`; bijective
__device__ __forceinline__ int sw_off(int r, int v) {
    return r * SST + (((v) ^ (r & 15)) << 3);
}

// ---------------- pad-copy: x [B,T,76] f32 -> h [Bc,T,80] bf16 ----------------
__global__ __launch_bounds__(256) void pad_copy_kernel(
    const float* __restrict__ x, __bf16* __restrict__ h, int b0)
{
    int bl = blockIdx.y;
    int q  = blockIdx.x * 256 + threadIdx.x;
    int t  = q / 20, c4 = (q - t * 20) * 4;
    float4 v = {0.f, 0.f, 0.f, 0.f};
    if (c4 < F_CH)
        v = *(const float4*)(x + ((size_t)(b0 + bl) * T_LEN + t) * F_CH + c4);
    bf16x4 p;
    p[0] = (__bf16)v.x; p[1] = (__bf16)v.y; p[2] = (__bf16)v.z; p[3] = (__bf16)v.w;
    *(bf16x4*)(h + ((size_t)bl * T_LEN + t) * HP + c4) = p;
}

// ---- weight prep: cw [76][76][3] f32 -> wpb [3][96][WSTR] bf16 (zero-padded) ----
__global__ __launch_bounds__(256) void wprep_kernel(
    const float* __restrict__ cw, __bf16* __restrict__ wpb)
{
    int idx = blockIdx.x * 256 + threadIdx.x;
    if (idx >= 3 * 96 * WSTR) return;
    int tap = idx / (96 * WSTR);
    int rem = idx - tap * 96 * WSTR;
    int c = rem / WSTR, ci = rem - c * WSTR;
    float v = 0.0f;
    if (c < F_CH && ci < F_CH) v = cw[((size_t)c * F_CH + ci) * 3 + tap];
    wpb[idx] = (__bf16)v;
}

// one conv eval: all 3 taps from register A-fragments
__device__ __forceinline__ f32x16 conv_eval(
    const __bf16* __restrict__ sb, int rb, int l5, const bf16x8 afr[3][NKB])
{
    f32x16 a = {};
    #pragma unroll
    for (int tap = 0; tap < 3; ++tap) {
        #pragma unroll
        for (int kb = 0; kb < NKB; ++kb) {
            bf16x8 bf = *(const bf16x8*)&sb[sw_off(rb + tap, kb * 2 + l5)];
            a = __builtin_amdgcn_mfma_f32_32x32x16_bf16(afr[tap][kb], bf, a, 0, 0, 0);
        }
    }
    return a;
}

// ---------- dual-slab single RK4 step: hout = h + dt/6 (k1+2k2+2k3+k4) ----------
__global__ __launch_bounds__(TPB, 2) void rk4_step_kernel(
    const __bf16* __restrict__ hin, __bf16* __restrict__ hout,
    const __bf16* __restrict__ wpb, const float* __restrict__ cb)
{
    __shared__ __bf16 s_lds[3][SROWS * SST];
    __shared__ float  cb_lds[96];

    const int b    = blockIdx.y;
    const int T0A  = blockIdx.x * BLKW;
    const int T0B  = T0A + SLABW;
    const int tid  = threadIdx.x;
    const int lane = tid & 63;
    const int l31  = lane & 31;
    const int l5   = lane >> 5;          // 0..1
    const int wv   = tid >> 6;           // 0..5
    const int ct   = wv >> 1;            // c-tile 0..2
    const int tq   = wv & 1;             // t-tile 0..1

    const int  rb   = tq * 32 + l31;     // row base 0..63
    const int  tgA  = T0A - HALO + rb;
    const int  tgB  = T0B - HALO + rb;
    const bool tokA = (tgA >= 0 && tgA < T_LEN);
    const bool tokB = (tgB >= 0 && tgB < T_LEN);

    // zero the 6 halo rows (3 buffers x rows {0, SROWS-1} x 64 dwords)
    {
        int buf = tid / 128, rr = (tid % 128) / 64, c = tid % 64;
        ((uint32_t*)&s_lds[buf][(rr ? (SROWS - 1) : 0) * SST])[c] = 0u;
    }
    if (tid < 96) cb_lds[tid] = (tid < F_CH) ? cb[tid] * C2LOG2E : 0.0f;

    // ---- load h (bf16) for both slabs ----
    float  hnA[16], hnB[16];
    bf16x4 hpkA[4], hpkB[4];
    const __bf16* hb = hin + (size_t)b * T_LEN * HP;
    #pragma unroll
    for (int q = 0; q < 4; ++q) {
        int c0 = ct * 32 + l5 * 4 + q * 8;
        bf16x4 vA = {}, vB = {};
        if (c0 < HP) {
            if (tokA) vA = *(const bf16x4*)(hb + (size_t)tgA * HP + c0);
            if (tokB) vB = *(const bf16x4*)(hb + (size_t)tgB * HP + c0);
        }
        hpkA[q] = vA; hpkB[q] = vB;
        hnA[q*4+0] = (float)vA[0]; hnA[q*4+1] = (float)vA[1];
        hnA[q*4+2] = (float)vA[2]; hnA[q*4+3] = (float)vA[3];
        hnB[q*4+0] = (float)vB[0]; hnB[q*4+1] = (float)vB[1];
        hnB[q*4+2] = (float)vB[2]; hnB[q*4+3] = (float)vB[3];
    }

    // ---- A fragments: all 3 taps x 5 k-blocks in registers (60 VGPR) ----
    bf16x8 afr[3][NKB];
    #pragma unroll
    for (int tap = 0; tap < 3; ++tap)
        #pragma unroll
        for (int kb = 0; kb < NKB; ++kb)
            afr[tap][kb] = *(const bf16x8*)&wpb[((size_t)tap * 96 + ct * 32 + l31) * WSTR
                                                + kb * 16 + l5 * 8];

    __bf16* p0 = s_lds[0];
    __bf16* p1 = s_lds[1];
    __bf16* p2 = s_lds[2];

    // ---- prologue: stage A -> p0 ; bar ; MFMA_A(0) + stage B -> p2 ; bar ----
    #pragma unroll
    for (int q = 0; q < 4; ++q) {
        int c0 = ct * 32 + l5 * 4 + q * 8;
        if (c0 < HP) *(bf16x4*)&p0[sw_off(rb + 1, ct * 4 + q) + l5 * 4] = hpkA[q];
    }
    __syncthreads();

    f32x16 accA = conv_eval(p0, rb, l5, afr);
    #pragma unroll
    for (int q = 0; q < 4; ++q) {
        int c0 = ct * 32 + l5 * 4 + q * 8;
        if (c0 < HP) *(bf16x4*)&p2[sw_off(rb + 1, ct * 4 + q) + l5 * 4] = hpkB[q];
    }
    __syncthreads();

    const float dt = 0.125f;
    f32x16 accB;

#define EPI(acc, hn, hpk, tokX, swp)                                          \
    {                                                                         \
        const float al_t = (tokX) ? al : 0.0f;                                \
        _Pragma("unroll")                                                     \
        for (int q = 0; q < 4; ++q) {                                         \
            int c0 = ct * 32 + l5 * 4 + q * 8;                                \
            if (c0 >= HP) continue;                                           \
            f32x4 bias = *(const f32x4*)&cb_lds[c0];                          \
            bf16x4 p;                                                         \
            _Pragma("unroll")                                                 \
            for (int j = 0; j < 4; ++j) {                                     \
                float y  = fmaf((acc)[q*4+j], C2LOG2E, bias[j]);              \
                float ex = __builtin_amdgcn_exp2f(y);                         \
                float kv = fmaf(-2.0f, __builtin_amdgcn_rcpf(ex + 1.0f), 1.0f); \
                (hn)[q*4+j] = fmaf(we, kv, (hn)[q*4+j]);                      \
                p[j] = (__bf16)fmaf(al_t, kv, (float)(hpk)[q][j]);            \
            }                                                                 \
            if (!laststage)                                                   \
                *(bf16x4*)&(swp)[sw_off(rb + 1, ct * 4 + q) + l5 * 4] = p;    \
        }                                                                     \
    }

    #pragma unroll 1
    for (int ge = 0; ge < 4; ++ge) {
        const float we = (ge == 0 || ge == 3) ? dt / 6.0f : dt / 3.0f;
        const float al = (ge == 2) ? dt : 0.5f * dt;
        const bool laststage = (ge == 3);

        // HP1: MFMA_B(ge) reads p2 || EPI_A(ge) writes p1
        accB = conv_eval(p2, rb, l5, afr);
        EPI(accA, hnA, hpkA, tokA, p1);
        __syncthreads();

        // HP2: MFMA_A(ge+1) reads p1 || EPI_B(ge) writes p0
        if (ge < 3) accA = conv_eval(p1, rb, l5, afr);
        EPI(accB, hnB, hpkB, tokB, p0);
        if (ge < 3) __syncthreads();

        // rotate buffers
        __bf16* t = p0; p0 = p1; p1 = p2; p2 = t;
    }
#undef EPI

    // ---- store both slabs (valid rows [HALO, HALO+SLABW)) ----
    __bf16* ho = hout + (size_t)b * T_LEN * HP;
    if (rb >= HALO && rb < HALO + SLABW && tgA < T_LEN) {
        #pragma unroll
        for (int q = 0; q < 4; ++q) {
            int c0 = ct * 32 + l5 * 4 + q * 8;
            if (c0 < HP) {
                bf16x4 p;
                p[0] = (__bf16)hnA[q*4+0]; p[1] = (__bf16)hnA[q*4+1];
                p[2] = (__bf16)hnA[q*4+2]; p[3] = (__bf16)hnA[q*4+3];
                *(bf16x4*)(ho + (size_t)tgA * HP + c0) = p;
            }
        }
    }
    if (rb >= HALO && rb < HALO + SLABW && tgB < T_LEN) {
        #pragma unroll
        for (int q = 0; q < 4; ++q) {
            int c0 = ct * 32 + l5 * 4 + q * 8;
            if (c0 < HP) {
                bf16x4 p;
                p[0] = (__bf16)hnB[q*4+0]; p[1] = (__bf16)hnB[q*4+1];
                p[2] = (__bf16)hnB[q*4+2]; p[3] = (__bf16)hnB[q*4+3];
                *(bf16x4*)(ho + (size_t)tgB * HP + c0) = p;
            }
        }
    }
}

// ------------- final linear: out[b,t,c] = sum_f h[t][f]*fw[c,f] + fb[c] -------------
__global__ __launch_bounds__(256) void final_kernel(
    const __bf16* __restrict__ h, const float* __restrict__ fw,
    const float* __restrict__ fb, float* __restrict__ out, int b0)
{
    int bl = blockIdx.y;
    int t  = blockIdx.x * 256 + threadIdx.x;
    const __bf16* hr = h + ((size_t)bl * T_LEN + t) * HP;
    float acc[C_CLS];
#pragma unroll
    for (int c = 0; c < C_CLS; ++c) acc[c] = fb[c];
#pragma unroll
    for (int qf = 0; qf < 19; ++qf) {
        bf16x4 v4 = *(const bf16x4*)(hr + qf * 4);
        float v0 = (float)v4[0], v1 = (float)v4[1], v2 = (float)v4[2], v3 = (float)v4[3];
#pragma unroll
        for (int c = 0; c < C_CLS; ++c) {
            const float* w = fw + c * F_CH + qf * 4;
            acc[c] = fmaf(w[0], v0, acc[c]);
            acc[c] = fmaf(w[1], v1, acc[c]);
            acc[c] = fmaf(w[2], v2, acc[c]);
            acc[c] = fmaf(w[3], v3, acc[c]);
        }
    }
    float* ob = out + ((size_t)(b0 + bl) * T_LEN + t) * C_CLS;
#pragma unroll
    for (int c = 0; c < C_CLS; ++c) ob[c] = acc[c];
}

extern "C" void kernel_launch(void* const* d_in, const int* in_sizes, int n_in,
                              void* d_out, int out_size, void* d_ws, size_t ws_size,
                              hipStream_t stream)
{
    const float* x  = (const float*)d_in[0];
    const float* cw = (const float*)d_in[1];
    const float* cb = (const float*)d_in[2];
    const float* fw = (const float*)d_in[3];
    const float* fb = (const float*)d_in[4];
    float* out = (float*)d_out;

    const size_t FT = (size_t)T_LEN * HP;            // bf16 elems per batch plane

    __bf16* WPB = (__bf16*)d_ws;
    const size_t wpbBytes = 51200;                   // 3*96*88 bf16, padded/aligned
    __bf16* planes = (__bf16*)((char*)d_ws + wpbBytes);

    size_t planeBytes = 2 * FT * sizeof(__bf16);
    size_t avail = ws_size - wpbBytes;
    int Bc = (int)(avail / planeBytes);
    if (Bc > B_TOT) Bc = B_TOT;
    if (Bc < 1) Bc = 1;

    __bf16* H0 = planes;
    __bf16* H1 = H0 + (size_t)Bc * FT;

    wprep_kernel<<<(3 * 96 * WSTR + 255) / 256, 256, 0, stream>>>(cw, WPB);

    for (int b0 = 0; b0 < B_TOT; b0 += Bc) {
        int bc = (B_TOT - b0 < Bc) ? (B_TOT - b0) : Bc;

        dim3 gP(T_LEN * 20 / 256, bc);
        pad_copy_kernel<<<gP, 256, 0, stream>>>(x, H0, b0);

        __bf16* hcur = H0;
        __bf16* hnxt = H1;
        dim3 gR(NBT, bc);
        for (int st = 0; st < NSTEP; ++st) {
            rk4_step_kernel<<<gR, TPB, 0, stream>>>(hcur, hnxt, WPB, cb);
            __bf16* tmp = hcur; hcur = hnxt; hnxt = tmp;
        }

        dim3 gF(T_LEN / 256, bc);
        final_kernel<<<gF, 256, 0, stream>>>(hcur, fw, fb, out, b0);
    }
}